// Round 9
// baseline (2450.848 us; speedup 1.0000x reference)
//
#include <hip/hip_runtime.h>
#include <hip/hip_bf16.h>

// Sizes fixed by the problem
#define BB 128
#define SS 1024
#define FF 512
#define HH 128
#define G3 384   // 3*H

typedef __attribute__((ext_vector_type(8))) short bf16x8;
typedef __attribute__((ext_vector_type(4))) float f32x4;
typedef _Float16 half2_t __attribute__((ext_vector_type(2)));

// ---------------------------------------------------------------------------
// lengths: len[b] = #rows t with sum_f x[b,t,f] != 0
// ---------------------------------------------------------------------------
__global__ void zero_len_kernel(int* len) { len[threadIdx.x] = 0; }

__global__ void lengths_kernel(const float* __restrict__ x, int* __restrict__ len) {
    int wave = threadIdx.x >> 6;
    int lane = threadIdx.x & 63;
    long row = (long)blockIdx.x * 4 + wave;   // 0 .. 131071
    const float4* p = (const float4*)&x[row * FF + lane * 8];
    float4 v0 = p[0], v1 = p[1];
    float s = v0.x + v0.y + v0.z + v0.w + v1.x + v1.y + v1.z + v1.w;
    #pragma unroll
    for (int off = 32; off > 0; off >>= 1) s += __shfl_down(s, off, 64);
    if (lane == 0 && s != 0.0f) atomicAdd(&len[row >> 10], 1);
}

// rank[i] = stable rank under descending-length sort (ties -> lower index first)
__global__ void rank_kernel(const int* __restrict__ len, int* __restrict__ rank) {
    int i = threadIdx.x;
    int li = len[i];
    int r = 0;
    for (int jj = 0; jj < BB; jj++) {
        int lj = len[jj];
        if (lj > li || (lj == li && jj < i)) r++;
    }
    rank[i] = r;
}

// ---------------------------------------------------------------------------
// bf16 split helpers (RTN-even rounding; no NaN/inf in this data)
// ---------------------------------------------------------------------------
__device__ __forceinline__ short bf_hi(float w, float& hf) {
    unsigned u = __builtin_bit_cast(unsigned, w);
    unsigned r = (u + 0x7FFFu + ((u >> 16) & 1u)) & 0xFFFF0000u;
    hf = __builtin_bit_cast(float, r);
    return (short)(r >> 16);
}
__device__ __forceinline__ short bf_rn(float w) {
    unsigned u = __builtin_bit_cast(unsigned, w);
    unsigned r = u + 0x7FFFu + ((u >> 16) & 1u);
    return (short)(r >> 16);
}

// ---------------------------------------------------------------------------
// Split-bf16 MFMA GEMM: C[M,N] = A[M,K] @ W[N,K]^T + bias[N]
// (unchanged from round 6; 3-pass hh+hl+lh split -> fp32-grade accuracy)
// ---------------------------------------------------------------------------
__global__ __launch_bounds__(256) void gemm_mfma(
    const float* __restrict__ A, const float* __restrict__ W,
    const float* __restrict__ bias, float* __restrict__ C,
    int M, int N, int K)
{
    const int tid  = threadIdx.x;
    const int wvid = tid >> 6;
    const int lane = tid & 63;
    const int m0   = blockIdx.x * 64 + wvid * 16;
    const int n0   = blockIdx.y * 128;
    const int KS   = K >> 5;

    __shared__ __align__(16) short sh[2][8][64][8];   // [plane][ntile][lane][e] 16KB

    f32x4 acc[8];
    #pragma unroll
    for (int i = 0; i < 8; i++) acc[i] = (f32x4){0.f, 0.f, 0.f, 0.f};

    const int arow = m0 + (lane & 15);
    const int koff = (lane >> 4) << 3;

    for (int ks = 0; ks < KS; ks++) {
        __syncthreads();   // previous iteration's sh reads complete
        #pragma unroll
        for (int i = 0; i < 2; i++) {
            int p  = tid + i * 256;
            int nt = p >> 6, ln = p & 63;
            const float* src = &W[(size_t)(n0 + nt * 16 + (ln & 15)) * K
                                  + ks * 32 + ((ln >> 4) << 3)];
            float w8[8];
            *(float4*)&w8[0] = *(const float4*)&src[0];
            *(float4*)&w8[4] = *(const float4*)&src[4];
            short hi8[8], lo8[8];
            #pragma unroll
            for (int e = 0; e < 8; e++) {
                float hf; hi8[e] = bf_hi(w8[e], hf);
                lo8[e] = bf_rn(w8[e] - hf);
            }
            *(bf16x8*)&sh[0][nt][ln][0] = *(bf16x8*)hi8;
            *(bf16x8*)&sh[1][nt][ln][0] = *(bf16x8*)lo8;
        }
        const float* ap = &A[(size_t)arow * K + ks * 32 + koff];
        float av[8];
        *(float4*)&av[0] = *(const float4*)&ap[0];
        *(float4*)&av[4] = *(const float4*)&ap[4];
        short ah[8], al[8];
        #pragma unroll
        for (int e = 0; e < 8; e++) {
            float hf; ah[e] = bf_hi(av[e], hf);
            al[e] = bf_rn(av[e] - hf);
        }
        bf16x8 ahi = *(bf16x8*)ah, alo = *(bf16x8*)al;
        __syncthreads();   // sh ready
        #pragma unroll
        for (int nt = 0; nt < 8; nt++) {
            bf16x8 bhi = *(bf16x8*)&sh[0][nt][lane][0];
            bf16x8 blo = *(bf16x8*)&sh[1][nt][lane][0];
            acc[nt] = __builtin_amdgcn_mfma_f32_16x16x32_bf16(ahi, bhi, acc[nt], 0, 0, 0);
            acc[nt] = __builtin_amdgcn_mfma_f32_16x16x32_bf16(ahi, blo, acc[nt], 0, 0, 0);
            acc[nt] = __builtin_amdgcn_mfma_f32_16x16x32_bf16(alo, bhi, acc[nt], 0, 0, 0);
        }
    }
    const int crow = m0 + ((lane >> 4) << 2);
    const int ccol = n0 + (lane & 15);
    #pragma unroll
    for (int nt = 0; nt < 8; nt++) {
        int col = ccol + nt * 16;
        float bv = bias[col];
        #pragma unroll
        for (int r = 0; r < 4; r++)
            C[(size_t)(crow + r) * N + col] = acc[nt][r] + bv;
    }
}

// ---------------------------------------------------------------------------
// GRU recurrence, v9: 1024 threads/block, 24 weight VGPRs/thread.
// Rounds 3-8 post-mortem: regalloc targets ~56-88 VGPR for this kernel no
// matter what attributes/pins say, and satisfies in-loop "+v" pins by
// reloading from scratch/L2 each step (196 KB/step/block = 1640 cy/step =
// the whole kernel time, invariant across r3-r8 inner-loop variants).
// Fix: shrink per-thread weight demand 4x so residency fits under ANY
// plausible target. Thread (j = tid>>3, k8 = tid&7) owns 3 gate-rows j over
// k in [k8*16, k8*16+16): 48 f16 = 24 packed VGPRs. Total demand ~60 regs.
// Reduction over 8 k8-lanes via shfl_xor 1,2,4 (same wave). 24 fdot2/step.
// ---------------------------------------------------------------------------
__device__ __forceinline__ float fast_sigmoid(float x) {
    return __builtin_amdgcn_rcpf(1.0f + __expf(-x));
}
__device__ __forceinline__ float fast_tanh(float x) {
    return 1.0f - 2.0f * __builtin_amdgcn_rcpf(1.0f + __expf(2.0f * x));
}
__device__ __forceinline__ half2_t bc16(unsigned u) {
    return __builtin_bit_cast(half2_t, u);
}
__device__ __forceinline__ unsigned pk16(float x, float y) {
    half2_t h; h[0] = (_Float16)x; h[1] = (_Float16)y;
    return __builtin_bit_cast(unsigned, h);
}
__device__ __forceinline__ float fdot2_(half2_t a, half2_t b, float c) {
#if __has_builtin(__builtin_amdgcn_fdot2)
    return __builtin_amdgcn_fdot2(a, b, c, false);
#else
    return c + (float)a[0] * (float)b[0] + (float)a[1] * (float)b[1];
#endif
}

template<int FINAL>
__global__ __launch_bounds__(1024, 4) void gru_rec(
    const float* __restrict__ xg,    // [B,S,3H]
    const float* __restrict__ Whh,   // [3H,H]
    const float* __restrict__ bhh,   // [3H]
    float* __restrict__ h_out,       // [B,S,H] (FINAL=0) or [B,H] (FINAL=1)
    const int* __restrict__ len,
    const int* __restrict__ rank)
{
    const int b   = blockIdx.x;
    const int tid = threadIdx.x;
    const int j   = tid >> 3;     // 0..127 output lane
    const int k8  = tid & 7;      // K-sixteenth (16 elems = 8 f16 pairs)

    __shared__ __align__(16) _Float16 h16[2][HH];   // f16 hidden for dots
    __shared__ __align__(16) float    h32[2][HH];   // fp32 hidden for writeout

    // 3 gates x 8 f16-pair weights = 24 VGPRs
    unsigned wv[24];
    #pragma unroll
    for (int g = 0; g < 3; g++) {
        const float* wr = &Whh[(size_t)(g * HH + j) * HH + k8 * 16];
        #pragma unroll
        for (int m = 0; m < 8; m++) wv[g * 8 + m] = pk16(wr[2 * m], wr[2 * m + 1]);
    }

    float b_r = 0.f, b_z = 0.f, b_n = 0.f;
    if (k8 == 0) { b_r = bhh[j]; b_z = bhh[HH + j]; b_n = bhh[2 * HH + j]; }
    const float* xgb = xg + (size_t)b * SS * G3;

    if (tid < HH) { h16[0][tid] = (_Float16)0.f; h32[0][tid] = 0.f; }
    float hprev = 0.0f, osum = 0.0f;
    const int L = FINAL ? len[b] : 0;

    float xr = 0.f, xz = 0.f, xn = 0.f;
    if (k8 == 0) { xr = xgb[j]; xz = xgb[HH + j]; xn = xgb[2 * HH + j]; }
    __syncthreads();

    for (int t = 0; t < SS; t++) {
        // in-loop pin: keep the 24 packed weights loop-carried in VGPRs
        #pragma unroll
        for (int m = 0; m < 24; m += 4)
            asm volatile("" : "+v"(wv[m]), "+v"(wv[m + 1]),
                              "+v"(wv[m + 2]), "+v"(wv[m + 3]));

        // lagged coalesced global write of h_{t-1} (32 threads, float4)
        if (!FINAL && t > 0 && tid >= 64 && tid < 96) {
            int c = tid - 64;
            float4 hv = ((const float4*)h32[t & 1])[c];
            *(float4*)&h_out[((size_t)b * SS + (t - 1)) * HH + c * 4] = hv;
        }
        // prefetch xg for t+1
        float nxr = 0.f, nxz = 0.f, nxn = 0.f;
        if (k8 == 0 && t + 1 < SS) {
            const float* p = xgb + (size_t)(t + 1) * G3;
            nxr = p[j]; nxz = p[HH + j]; nxn = p[2 * HH + j];
        }
        // h slice: 16 f16 = 2 uint4 (broadcast within same-k8 lanes; 2-way
        // bank aliasing across k8, free per m136)
        const unsigned* hp = (const unsigned*)(&h16[t & 1][0]) + k8 * 8;
        uint4 hv0 = *(const uint4*)hp;
        uint4 hv1 = *(const uint4*)(hp + 4);
        half2_t q0 = bc16(hv0.x), q1 = bc16(hv0.y), q2 = bc16(hv0.z), q3 = bc16(hv0.w);
        half2_t q4 = bc16(hv1.x), q5 = bc16(hv1.y), q6 = bc16(hv1.z), q7 = bc16(hv1.w);

        // 3 gates x 8 fdot2, 2 chains per gate
        float a0, a1, a2, c0, c1, c2;
        a0 = fdot2_(bc16(wv[0]),  q0, 0.f); c0 = fdot2_(bc16(wv[1]),  q1, 0.f);
        a0 = fdot2_(bc16(wv[2]),  q2, a0);  c0 = fdot2_(bc16(wv[3]),  q3, c0);
        a0 = fdot2_(bc16(wv[4]),  q4, a0);  c0 = fdot2_(bc16(wv[5]),  q5, c0);
        a0 = fdot2_(bc16(wv[6]),  q6, a0);  c0 = fdot2_(bc16(wv[7]),  q7, c0);
        a1 = fdot2_(bc16(wv[8]),  q0, 0.f); c1 = fdot2_(bc16(wv[9]),  q1, 0.f);
        a1 = fdot2_(bc16(wv[10]), q2, a1);  c1 = fdot2_(bc16(wv[11]), q3, c1);
        a1 = fdot2_(bc16(wv[12]), q4, a1);  c1 = fdot2_(bc16(wv[13]), q5, c1);
        a1 = fdot2_(bc16(wv[14]), q6, a1);  c1 = fdot2_(bc16(wv[15]), q7, c1);
        a2 = fdot2_(bc16(wv[16]), q0, 0.f); c2 = fdot2_(bc16(wv[17]), q1, 0.f);
        a2 = fdot2_(bc16(wv[18]), q2, a2);  c2 = fdot2_(bc16(wv[19]), q3, c2);
        a2 = fdot2_(bc16(wv[20]), q4, a2);  c2 = fdot2_(bc16(wv[21]), q5, c2);
        a2 = fdot2_(bc16(wv[22]), q6, a2);  c2 = fdot2_(bc16(wv[23]), q7, c2);

        float s0 = a0 + c0, s1 = a1 + c1, s2 = a2 + c2;
        s0 += __shfl_xor(s0, 1, 64); s1 += __shfl_xor(s1, 1, 64); s2 += __shfl_xor(s2, 1, 64);
        s0 += __shfl_xor(s0, 2, 64); s1 += __shfl_xor(s1, 2, 64); s2 += __shfl_xor(s2, 2, 64);
        s0 += __shfl_xor(s0, 4, 64); s1 += __shfl_xor(s1, 4, 64); s2 += __shfl_xor(s2, 4, 64);

        if (k8 == 0) {
            float r = fast_sigmoid(xr + s0 + b_r);
            float z = fast_sigmoid(xz + s1 + b_z);
            float n = fast_tanh(xn + r * (s2 + b_n));
            float h = (1.0f - z) * n + z * hprev;
            hprev = h;
            h16[(t + 1) & 1][j] = (_Float16)h;
            h32[(t + 1) & 1][j] = h;
            if (FINAL) { if (t < L) osum += h; }
        }
        xr = nxr; xz = nxz; xn = nxn;
        __syncthreads();
    }
    if (!FINAL && tid >= 64 && tid < 96) {
        int c = tid - 64;
        float4 hv = ((const float4*)h32[SS & 1])[c];
        *(float4*)&h_out[((size_t)b * SS + (SS - 1)) * HH + c * 4] = hv;
    }
    if (FINAL && k8 == 0) {
        h_out[(size_t)rank[b] * HH + j] = osum * (1.0f / (float)SS);
    }
}

// ---------------------------------------------------------------------------
extern "C" void kernel_launch(void* const* d_in, const int* in_sizes, int n_in,
                              void* d_out, int out_size, void* d_ws, size_t ws_size,
                              hipStream_t stream) {
    const float* x    = (const float*)d_in[0];
    const float* Wp   = (const float*)d_in[1];
    const float* bp   = (const float*)d_in[2];
    const float* Wih0 = (const float*)d_in[3];
    const float* Whh0 = (const float*)d_in[4];
    const float* bih0 = (const float*)d_in[5];
    const float* bhh0 = (const float*)d_in[6];
    const float* Wih1 = (const float*)d_in[7];
    const float* Whh1 = (const float*)d_in[8];
    const float* bih1 = (const float*)d_in[9];
    const float* bhh1 = (const float*)d_in[10];
    float* out = (float*)d_out;

    // workspace: [len 128 int][rank 128 int] ... 4KB ... proj/h1 (64MB), xg (192MB)
    int* len  = (int*)d_ws;
    int* rank = len + 128;
    float* proj = (float*)((char*)d_ws + 4096);                  // [B*S, H]  reused as h1
    float* xgb  = proj + (size_t)BB * SS * HH;                   // [B*S, 3H]

    // 1) lengths + rank
    zero_len_kernel<<<1, 128, 0, stream>>>(len);
    lengths_kernel<<<(BB * SS) / 4, 256, 0, stream>>>(x, len);
    rank_kernel<<<1, 128, 0, stream>>>(len, rank);

    // 2) proj = x @ Wp^T + bp       [131072,512] x [128,512]^T
    gemm_mfma<<<dim3(BB * SS / 64, 1), 256, 0, stream>>>(x, Wp, bp, proj,
                                                         BB * SS, HH, FF);
    // 3) xg0 = proj @ Wih0^T + bih0 [131072,128] x [384,128]^T
    gemm_mfma<<<dim3(BB * SS / 64, 3), 256, 0, stream>>>(proj, Wih0, bih0, xgb,
                                                         BB * SS, G3, HH);
    // 4) layer-1 recurrence -> h1 (into proj region; proj is dead now)
    gru_rec<0><<<BB, 1024, 0, stream>>>(xgb, Whh0, bhh0, proj, len, rank);

    // 5) xg1 = h1 @ Wih1^T + bih1 (overwrite xg region)
    gemm_mfma<<<dim3(BB * SS / 64, 3), 256, 0, stream>>>(proj, Wih1, bih1, xgb,
                                                         BB * SS, G3, HH);
    // 6) layer-2 recurrence + masked mean -> out at sorted rank
    gru_rec<1><<<BB, 1024, 0, stream>>>(xgb, Whh1, bhh1, out, len, rank);
}

// Round 10
// 2162.224 us; speedup vs baseline: 1.1335x; 1.1335x over previous
//
#include <hip/hip_runtime.h>
#include <hip/hip_bf16.h>

// Sizes fixed by the problem
#define BB 128
#define SS 1024
#define FF 512
#define HH 128
#define G3 384   // 3*H

typedef __attribute__((ext_vector_type(8))) short bf16x8;
typedef __attribute__((ext_vector_type(4))) float f32x4;
typedef _Float16 half2_t __attribute__((ext_vector_type(2)));

// ---------------------------------------------------------------------------
// lengths: len[b] = #rows t with sum_f x[b,t,f] != 0
// ---------------------------------------------------------------------------
__global__ void zero_len_kernel(int* len) { len[threadIdx.x] = 0; }

__global__ void lengths_kernel(const float* __restrict__ x, int* __restrict__ len) {
    int wave = threadIdx.x >> 6;
    int lane = threadIdx.x & 63;
    long row = (long)blockIdx.x * 4 + wave;   // 0 .. 131071
    const float4* p = (const float4*)&x[row * FF + lane * 8];
    float4 v0 = p[0], v1 = p[1];
    float s = v0.x + v0.y + v0.z + v0.w + v1.x + v1.y + v1.z + v1.w;
    #pragma unroll
    for (int off = 32; off > 0; off >>= 1) s += __shfl_down(s, off, 64);
    if (lane == 0 && s != 0.0f) atomicAdd(&len[row >> 10], 1);
}

// rank[i] = stable rank under descending-length sort (ties -> lower index first)
__global__ void rank_kernel(const int* __restrict__ len, int* __restrict__ rank) {
    int i = threadIdx.x;
    int li = len[i];
    int r = 0;
    for (int jj = 0; jj < BB; jj++) {
        int lj = len[jj];
        if (lj > li || (lj == li && jj < i)) r++;
    }
    rank[i] = r;
}

// ---------------------------------------------------------------------------
// bf16 split helpers (RTN-even rounding; no NaN/inf in this data)
// ---------------------------------------------------------------------------
__device__ __forceinline__ short bf_hi(float w, float& hf) {
    unsigned u = __builtin_bit_cast(unsigned, w);
    unsigned r = (u + 0x7FFFu + ((u >> 16) & 1u)) & 0xFFFF0000u;
    hf = __builtin_bit_cast(float, r);
    return (short)(r >> 16);
}
__device__ __forceinline__ short bf_rn(float w) {
    unsigned u = __builtin_bit_cast(unsigned, w);
    unsigned r = u + 0x7FFFu + ((u >> 16) & 1u);
    return (short)(r >> 16);
}

// ---------------------------------------------------------------------------
// Split-bf16 MFMA GEMM: C[M,N] = A[M,K] @ W[N,K]^T + bias[N]
// (unchanged from round 6; 3-pass hh+hl+lh split -> fp32-grade accuracy)
// ---------------------------------------------------------------------------
__global__ __launch_bounds__(256) void gemm_mfma(
    const float* __restrict__ A, const float* __restrict__ W,
    const float* __restrict__ bias, float* __restrict__ C,
    int M, int N, int K)
{
    const int tid  = threadIdx.x;
    const int wvid = tid >> 6;
    const int lane = tid & 63;
    const int m0   = blockIdx.x * 64 + wvid * 16;
    const int n0   = blockIdx.y * 128;
    const int KS   = K >> 5;

    __shared__ __align__(16) short sh[2][8][64][8];   // [plane][ntile][lane][e] 16KB

    f32x4 acc[8];
    #pragma unroll
    for (int i = 0; i < 8; i++) acc[i] = (f32x4){0.f, 0.f, 0.f, 0.f};

    const int arow = m0 + (lane & 15);
    const int koff = (lane >> 4) << 3;

    for (int ks = 0; ks < KS; ks++) {
        __syncthreads();   // previous iteration's sh reads complete
        #pragma unroll
        for (int i = 0; i < 2; i++) {
            int p  = tid + i * 256;
            int nt = p >> 6, ln = p & 63;
            const float* src = &W[(size_t)(n0 + nt * 16 + (ln & 15)) * K
                                  + ks * 32 + ((ln >> 4) << 3)];
            float w8[8];
            *(float4*)&w8[0] = *(const float4*)&src[0];
            *(float4*)&w8[4] = *(const float4*)&src[4];
            short hi8[8], lo8[8];
            #pragma unroll
            for (int e = 0; e < 8; e++) {
                float hf; hi8[e] = bf_hi(w8[e], hf);
                lo8[e] = bf_rn(w8[e] - hf);
            }
            *(bf16x8*)&sh[0][nt][ln][0] = *(bf16x8*)hi8;
            *(bf16x8*)&sh[1][nt][ln][0] = *(bf16x8*)lo8;
        }
        const float* ap = &A[(size_t)arow * K + ks * 32 + koff];
        float av[8];
        *(float4*)&av[0] = *(const float4*)&ap[0];
        *(float4*)&av[4] = *(const float4*)&ap[4];
        short ah[8], al[8];
        #pragma unroll
        for (int e = 0; e < 8; e++) {
            float hf; ah[e] = bf_hi(av[e], hf);
            al[e] = bf_rn(av[e] - hf);
        }
        bf16x8 ahi = *(bf16x8*)ah, alo = *(bf16x8*)al;
        __syncthreads();   // sh ready
        #pragma unroll
        for (int nt = 0; nt < 8; nt++) {
            bf16x8 bhi = *(bf16x8*)&sh[0][nt][lane][0];
            bf16x8 blo = *(bf16x8*)&sh[1][nt][lane][0];
            acc[nt] = __builtin_amdgcn_mfma_f32_16x16x32_bf16(ahi, bhi, acc[nt], 0, 0, 0);
            acc[nt] = __builtin_amdgcn_mfma_f32_16x16x32_bf16(ahi, blo, acc[nt], 0, 0, 0);
            acc[nt] = __builtin_amdgcn_mfma_f32_16x16x32_bf16(alo, bhi, acc[nt], 0, 0, 0);
        }
    }
    const int crow = m0 + ((lane >> 4) << 2);
    const int ccol = n0 + (lane & 15);
    #pragma unroll
    for (int nt = 0; nt < 8; nt++) {
        int col = ccol + nt * 16;
        float bv = bias[col];
        #pragma unroll
        for (int r = 0; r < 4; r++)
            C[(size_t)(crow + r) * N + col] = acc[nt][r] + bv;
    }
}

// ---------------------------------------------------------------------------
// f16 helpers
// ---------------------------------------------------------------------------
__device__ __forceinline__ float fast_sigmoid(float x) {
    return __builtin_amdgcn_rcpf(1.0f + __expf(-x));
}
__device__ __forceinline__ float fast_tanh(float x) {
    return 1.0f - 2.0f * __builtin_amdgcn_rcpf(1.0f + __expf(2.0f * x));
}
__device__ __forceinline__ half2_t bc16(unsigned u) {
    return __builtin_bit_cast(half2_t, u);
}
__device__ __forceinline__ unsigned pk16(float x, float y) {
    half2_t h; h[0] = (_Float16)x; h[1] = (_Float16)y;
    return __builtin_bit_cast(unsigned, h);
}
__device__ __forceinline__ float fdot2_(half2_t a, half2_t b, float c) {
#if __has_builtin(__builtin_amdgcn_fdot2)
    return __builtin_amdgcn_fdot2(a, b, c, false);
#else
    return c + (float)a[0] * (float)b[0] + (float)a[1] * (float)b[1];
#endif
}

// ---------------------------------------------------------------------------
// pack Whh (fp32 [3H][H]) -> f16 quads in the gru thread read order:
// wp[r*512 + tid], r = g*4+i, thread tid -> (j = tid>>2, kq = tid&3);
// quad covers Whh[g*H + j][kq*32 + i*8 .. +8).
// ---------------------------------------------------------------------------
__global__ void pack_whh(const float* __restrict__ Whh, uint4* __restrict__ wp) {
    int tid = threadIdx.x, r = blockIdx.x;
    int g = r >> 2, i = r & 3, j = tid >> 2, kq = tid & 3;
    const float* src = &Whh[(size_t)(g * HH + j) * HH + kq * 32 + i * 8];
    uint4 o;
    o.x = pk16(src[0], src[1]);
    o.y = pk16(src[2], src[3]);
    o.z = pk16(src[4], src[5]);
    o.w = pk16(src[6], src[7]);
    wp[r * 512 + tid] = o;
}

// ---------------------------------------------------------------------------
// GRU recurrence, v10: weights live in LDS, streamed per step.
// Rounds 3-9 post-mortem: the compiler will NOT keep a weight array in VGPRs
// across a barrier loop (remat/scratch reloads = 192 KB/step/block via L2 =
// 1640 cy/step = the whole kernel; "+v" pins are satisfied by reloading at
// the asm point). So give up on register residency: stage f16 weights in
// LDS (96 KB, fits; residency is structural). Per step each thread
// ds_read_b128s its 12 weight quads + 4 broadcast h quads: ~128 KB/step at
// 256 B/cy = ~500 cy/step, ~3x faster than the L2 path. The per-iteration
// opaque 'base' asm defeats LICM re-hoisting the (loop-invariant-address)
// LDS reads into spilled registers.
// ---------------------------------------------------------------------------
template<int FINAL>
__global__ __launch_bounds__(512) void gru_rec(
    const uint4* __restrict__ wp,    // [12*512] packed f16 weights
    const float* __restrict__ xg,    // [B,S,3H]
    const float* __restrict__ bhh,   // [3H]
    float* __restrict__ h_out,       // [B,S,H] (FINAL=0) or [B,H] (FINAL=1)
    const int* __restrict__ len,
    const int* __restrict__ rank)
{
    const int b   = blockIdx.x;
    const int tid = threadIdx.x;
    const int j   = tid >> 2;     // 0..127 output lane
    const int kq  = tid & 3;      // K-quarter (32 elems)

    __shared__ __align__(16) uint4    wlds[12 * 512];   // 96 KB f16 weights
    __shared__ __align__(16) _Float16 h16[2][HH];
    __shared__ __align__(16) float    h32[2][HH];

    // one-time stage: global (coalesced) -> LDS
    #pragma unroll
    for (int r = 0; r < 12; r++) wlds[r * 512 + tid] = wp[r * 512 + tid];

    float b_r = 0.f, b_z = 0.f, b_n = 0.f;
    if (kq == 0) { b_r = bhh[j]; b_z = bhh[HH + j]; b_n = bhh[2 * HH + j]; }
    const float* xgb = xg + (size_t)b * SS * G3;

    if (tid < HH) { h16[0][tid] = (_Float16)0.f; h32[0][tid] = 0.f; }
    float hprev = 0.0f, osum = 0.0f;
    const int L = FINAL ? len[b] : 0;

    float xr = 0.f, xz = 0.f, xn = 0.f;
    if (kq == 0) { xr = xgb[j]; xz = xgb[HH + j]; xn = xgb[2 * HH + j]; }
    __syncthreads();

    for (int t = 0; t < SS; t++) {
        // opaque base: the weight-read addresses become loop-variant to the
        // optimizer, so the 12 LDS reads stay INSIDE the loop (no LICM->spill)
        int base = 0;
        asm volatile("" : "+v"(base));
        const uint4* wlA = wlds + tid + base;             // r = 0..7  (offsets < 64KB)
        const uint4* wlB = wlds + 8 * 512 + tid + base;   // r = 8..11

        // lagged coalesced global write of h_{t-1} (wave 1)
        if (!FINAL && t > 0 && tid >= 64 && tid < 96) {
            int c = tid - 64;
            float4 hv = ((const float4*)h32[t & 1])[c];
            *(float4*)&h_out[((size_t)b * SS + (t - 1)) * HH + c * 4] = hv;
        }
        // prefetch xg for t+1
        float nxr = 0.f, nxz = 0.f, nxn = 0.f;
        if (kq == 0 && t + 1 < SS) {
            const float* p = xgb + (size_t)(t + 1) * G3;
            nxr = p[j]; nxz = p[HH + j]; nxn = p[2 * HH + j];
        }
        // h slice: 32 f16 = 4 uint4 (16-lane broadcast groups: free)
        const uint4* hp = (const uint4*)(&h16[t & 1][0]) + kq * 4;
        uint4 hq0 = hp[0], hq1 = hp[1], hq2 = hp[2], hq3 = hp[3];

        float s0, s1, s2;
        {   // gate r  (reads r=0..3)
            uint4 w0 = wlA[0 * 512], w1 = wlA[1 * 512], w2 = wlA[2 * 512], w3 = wlA[3 * 512];
            float aA = fdot2_(bc16(w0.x), bc16(hq0.x), 0.f);
            float aB = fdot2_(bc16(w0.y), bc16(hq0.y), 0.f);
            aA = fdot2_(bc16(w0.z), bc16(hq0.z), aA); aB = fdot2_(bc16(w0.w), bc16(hq0.w), aB);
            aA = fdot2_(bc16(w1.x), bc16(hq1.x), aA); aB = fdot2_(bc16(w1.y), bc16(hq1.y), aB);
            aA = fdot2_(bc16(w1.z), bc16(hq1.z), aA); aB = fdot2_(bc16(w1.w), bc16(hq1.w), aB);
            aA = fdot2_(bc16(w2.x), bc16(hq2.x), aA); aB = fdot2_(bc16(w2.y), bc16(hq2.y), aB);
            aA = fdot2_(bc16(w2.z), bc16(hq2.z), aA); aB = fdot2_(bc16(w2.w), bc16(hq2.w), aB);
            aA = fdot2_(bc16(w3.x), bc16(hq3.x), aA); aB = fdot2_(bc16(w3.y), bc16(hq3.y), aB);
            aA = fdot2_(bc16(w3.z), bc16(hq3.z), aA); aB = fdot2_(bc16(w3.w), bc16(hq3.w), aB);
            s0 = aA + aB;
        }
        {   // gate z  (reads r=4..7)
            uint4 w0 = wlA[4 * 512], w1 = wlA[5 * 512], w2 = wlA[6 * 512], w3 = wlA[7 * 512];
            float aA = fdot2_(bc16(w0.x), bc16(hq0.x), 0.f);
            float aB = fdot2_(bc16(w0.y), bc16(hq0.y), 0.f);
            aA = fdot2_(bc16(w0.z), bc16(hq0.z), aA); aB = fdot2_(bc16(w0.w), bc16(hq0.w), aB);
            aA = fdot2_(bc16(w1.x), bc16(hq1.x), aA); aB = fdot2_(bc16(w1.y), bc16(hq1.y), aB);
            aA = fdot2_(bc16(w1.z), bc16(hq1.z), aA); aB = fdot2_(bc16(w1.w), bc16(hq1.w), aB);
            aA = fdot2_(bc16(w2.x), bc16(hq2.x), aA); aB = fdot2_(bc16(w2.y), bc16(hq2.y), aB);
            aA = fdot2_(bc16(w2.z), bc16(hq2.z), aA); aB = fdot2_(bc16(w2.w), bc16(hq2.w), aB);
            aA = fdot2_(bc16(w3.x), bc16(hq3.x), aA); aB = fdot2_(bc16(w3.y), bc16(hq3.y), aB);
            aA = fdot2_(bc16(w3.z), bc16(hq3.z), aA); aB = fdot2_(bc16(w3.w), bc16(hq3.w), aB);
            s1 = aA + aB;
        }
        {   // gate n  (reads r=8..11)
            uint4 w0 = wlB[0 * 512], w1 = wlB[1 * 512], w2 = wlB[2 * 512], w3 = wlB[3 * 512];
            float aA = fdot2_(bc16(w0.x), bc16(hq0.x), 0.f);
            float aB = fdot2_(bc16(w0.y), bc16(hq0.y), 0.f);
            aA = fdot2_(bc16(w0.z), bc16(hq0.z), aA); aB = fdot2_(bc16(w0.w), bc16(hq0.w), aB);
            aA = fdot2_(bc16(w1.x), bc16(hq1.x), aA); aB = fdot2_(bc16(w1.y), bc16(hq1.y), aB);
            aA = fdot2_(bc16(w1.z), bc16(hq1.z), aA); aB = fdot2_(bc16(w1.w), bc16(hq1.w), aB);
            aA = fdot2_(bc16(w2.x), bc16(hq2.x), aA); aB = fdot2_(bc16(w2.y), bc16(hq2.y), aB);
            aA = fdot2_(bc16(w2.z), bc16(hq2.z), aA); aB = fdot2_(bc16(w2.w), bc16(hq2.w), aB);
            aA = fdot2_(bc16(w3.x), bc16(hq3.x), aA); aB = fdot2_(bc16(w3.y), bc16(hq3.y), aB);
            aA = fdot2_(bc16(w3.z), bc16(hq3.z), aA); aB = fdot2_(bc16(w3.w), bc16(hq3.w), aB);
            s2 = aA + aB;
        }

        s0 += __shfl_xor(s0, 1, 64); s1 += __shfl_xor(s1, 1, 64); s2 += __shfl_xor(s2, 1, 64);
        s0 += __shfl_xor(s0, 2, 64); s1 += __shfl_xor(s1, 2, 64); s2 += __shfl_xor(s2, 2, 64);

        if (kq == 0) {
            float r = fast_sigmoid(xr + s0 + b_r);
            float z = fast_sigmoid(xz + s1 + b_z);
            float n = fast_tanh(xn + r * (s2 + b_n));
            float h = (1.0f - z) * n + z * hprev;
            hprev = h;
            h16[(t + 1) & 1][j] = (_Float16)h;
            h32[(t + 1) & 1][j] = h;
            if (FINAL) { if (t < L) osum += h; }
        }
        xr = nxr; xz = nxz; xn = nxn;
        __syncthreads();
    }
    if (!FINAL && tid >= 64 && tid < 96) {
        int c = tid - 64;
        float4 hv = ((const float4*)h32[SS & 1])[c];
        *(float4*)&h_out[((size_t)b * SS + (SS - 1)) * HH + c * 4] = hv;
    }
    if (FINAL && kq == 0) {
        h_out[(size_t)rank[b] * HH + j] = osum * (1.0f / (float)SS);
    }
}

// ---------------------------------------------------------------------------
extern "C" void kernel_launch(void* const* d_in, const int* in_sizes, int n_in,
                              void* d_out, int out_size, void* d_ws, size_t ws_size,
                              hipStream_t stream) {
    const float* x    = (const float*)d_in[0];
    const float* Wp   = (const float*)d_in[1];
    const float* bp   = (const float*)d_in[2];
    const float* Wih0 = (const float*)d_in[3];
    const float* Whh0 = (const float*)d_in[4];
    const float* bih0 = (const float*)d_in[5];
    const float* bhh0 = (const float*)d_in[6];
    const float* Wih1 = (const float*)d_in[7];
    const float* Whh1 = (const float*)d_in[8];
    const float* bih1 = (const float*)d_in[9];
    const float* bhh1 = (const float*)d_in[10];
    float* out = (float*)d_out;

    // workspace: [len][rank] | wp0 96KB | wp1 96KB | proj 64MB | xg 192MB
    int* len  = (int*)d_ws;
    int* rank = len + 128;
    uint4* wp0 = (uint4*)((char*)d_ws + 4096);
    uint4* wp1 = wp0 + 12 * 512;
    float* proj = (float*)((char*)d_ws + 4096 + 2 * 12 * 512 * 16 + 4096); // reused as h1
    float* xgb  = proj + (size_t)BB * SS * HH;                             // [B*S, 3H]

    // 1) lengths + rank + weight packing
    zero_len_kernel<<<1, 128, 0, stream>>>(len);
    lengths_kernel<<<(BB * SS) / 4, 256, 0, stream>>>(x, len);
    rank_kernel<<<1, 128, 0, stream>>>(len, rank);
    pack_whh<<<12, 512, 0, stream>>>(Whh0, wp0);
    pack_whh<<<12, 512, 0, stream>>>(Whh1, wp1);

    // 2) proj = x @ Wp^T + bp       [131072,512] x [128,512]^T
    gemm_mfma<<<dim3(BB * SS / 64, 1), 256, 0, stream>>>(x, Wp, bp, proj,
                                                         BB * SS, HH, FF);
    // 3) xg0 = proj @ Wih0^T + bih0 [131072,128] x [384,128]^T
    gemm_mfma<<<dim3(BB * SS / 64, 3), 256, 0, stream>>>(proj, Wih0, bih0, xgb,
                                                         BB * SS, G3, HH);
    // 4) layer-1 recurrence -> h1 (into proj region; proj is dead now)
    gru_rec<0><<<BB, 512, 0, stream>>>(wp0, xgb, bhh0, proj, len, rank);

    // 5) xg1 = h1 @ Wih1^T + bih1 (overwrite xg region)
    gemm_mfma<<<dim3(BB * SS / 64, 3), 256, 0, stream>>>(proj, Wih1, bih1, xgb,
                                                         BB * SS, G3, HH);
    // 6) layer-2 recurrence + masked mean -> out at sorted rank
    gru_rec<1><<<BB, 512, 0, stream>>>(wp1, xgb, bhh1, out, len, rank);
}